// Round 1
// baseline (77.130 us; speedup 1.0000x reference)
//
#include <hip/hip_runtime.h>

#define B_DIM   1024
#define IN_DIM  1024
#define OUT_DIM 2048
#define NBITS   6
#define NENT    64   // 1 << NBITS

// ---------------------------------------------------------------------------
// Kernel 1: tiled transpose x (B x IN) -> xT (IN x B), so that the main
// kernel's per-bit gathers xT[m*B + b] are coalesced across b (lane dim).
// ---------------------------------------------------------------------------
__global__ __launch_bounds__(256) void transpose_x(const float* __restrict__ x,
                                                   float* __restrict__ xT) {
    __shared__ float tile[32][33];  // +1 pad: conflict-free transpose
    const int bx = blockIdx.x * 32;          // column offset in x (IN dim)
    const int by = blockIdx.y * 32;          // row offset in x (B dim)
    const int tx = threadIdx.x & 31;
    const int ty = threadIdx.x >> 5;         // 0..7
#pragma unroll
    for (int i = 0; i < 4; i++) {
        const int r = by + ty + i * 8;
        tile[ty + i * 8][tx] = x[r * IN_DIM + bx + tx];
    }
    __syncthreads();
#pragma unroll
    for (int i = 0; i < 4; i++) {
        const int r = bx + ty + i * 8;       // row of xT (IN dim)
        xT[r * B_DIM + by + tx] = tile[tx][ty + i * 8];
    }
}

// ---------------------------------------------------------------------------
// Kernel 2: one block per (o, b-tile of 256). lut row + mapping staged in LDS
// (wave-uniform -> broadcast reads). Each thread computes one out[b,o] via a
// 6-level binary fold over the 64-entry LUT: 63 x (mul+fma).
//   sm/sb: strides so the same kernel works with xT (sm=B,sb=1) or raw x
//   (sm=1,sb=IN) as a fallback when ws is too small.
// ---------------------------------------------------------------------------
__global__ __launch_bounds__(256) void lut_fwd(const float* __restrict__ xsrc,
                                               const float* __restrict__ lut,
                                               const int* __restrict__ mapping,
                                               float* __restrict__ out,
                                               int sm, int sb) {
    __shared__ float slut[NENT];
    __shared__ int   smap[NBITS];
    const int o = blockIdx.y;
    const int b = blockIdx.x * 256 + threadIdx.x;

    if (threadIdx.x < NENT)  slut[threadIdx.x] = lut[o * NENT + threadIdx.x];
    if (threadIdx.x < NBITS) smap[threadIdx.x] = mapping[o * NBITS + threadIdx.x];
    __syncthreads();

    // Gather the 6 selected x values for this b (coalesced when using xT).
    float xv[NBITS];
#pragma unroll
    for (int j = 0; j < NBITS; j++) {
        xv[j] = xsrc[smap[j] * sm + b * sb];
    }

    // Load LUT row into registers (LDS broadcast; compiler vectorizes b128).
    float v[NENT];
#pragma unroll
    for (int k = 0; k < NENT; k++) v[k] = slut[k];

    // Binary fold: contract bit j (LSB first).
    //   v'[m] = v[2m]*(1-x_j) + v[2m+1]*x_j
#pragma unroll
    for (int j = 0; j < NBITS; j++) {
        const float xj = xv[j];
        const float om = 1.0f - xj;
#pragma unroll
        for (int m = 0; m < (NENT >> (j + 1)); m++) {
            v[m] = fmaf(v[2 * m + 1], xj, v[2 * m] * om);
        }
    }

    out[(size_t)b * OUT_DIM + o] = v[0];
}

extern "C" void kernel_launch(void* const* d_in, const int* in_sizes, int n_in,
                              void* d_out, int out_size, void* d_ws, size_t ws_size,
                              hipStream_t stream) {
    const float* x       = (const float*)d_in[0];
    const float* lut     = (const float*)d_in[1];
    const int*   mapping = (const int*)d_in[2];
    float*       out     = (float*)d_out;

    const size_t xt_bytes = (size_t)B_DIM * IN_DIM * sizeof(float);
    const dim3 grid(B_DIM / 256, OUT_DIM);

    if (ws_size >= xt_bytes) {
        float* xT = (float*)d_ws;
        const dim3 tgrid(IN_DIM / 32, B_DIM / 32);
        transpose_x<<<tgrid, 256, 0, stream>>>(x, xT);
        lut_fwd<<<grid, 256, 0, stream>>>(xT, lut, mapping, out, B_DIM, 1);
    } else {
        // Fallback: gather directly from x (uncoalesced but correct).
        lut_fwd<<<grid, 256, 0, stream>>>(x, lut, mapping, out, 1, IN_DIM);
    }
}

// Round 2
// 76.976 us; speedup vs baseline: 1.0020x; 1.0020x over previous
//
#include <hip/hip_runtime.h>

#define B_DIM   1024
#define IN_DIM  1024
#define OUT_DIM 2048
#define NBITS   6
#define NENT    64   // 1 << NBITS

#define BT      64   // b per block
#define OT      32   // o per block (32 floats = one 128B line per out row)
#define OPT     8    // o per thread = OT / (256/BT)

// ---------------------------------------------------------------------------
// Kernel 1: tiled transpose x (B x IN) -> xT (IN x B) so main-kernel gathers
// xT[m*B + b] are coalesced across b.
// ---------------------------------------------------------------------------
__global__ __launch_bounds__(256) void transpose_x(const float* __restrict__ x,
                                                   float* __restrict__ xT) {
    __shared__ float tile[32][33];
    const int bx = blockIdx.x * 32;          // IN offset
    const int by = blockIdx.y * 32;          // B offset
    const int tx = threadIdx.x & 31;
    const int ty = threadIdx.x >> 5;         // 0..7
#pragma unroll
    for (int i = 0; i < 4; i++)
        tile[ty + i * 8][tx] = x[(by + ty + i * 8) * IN_DIM + bx + tx];
    __syncthreads();
#pragma unroll
    for (int i = 0; i < 4; i++)
        xT[(bx + ty + i * 8) * B_DIM + by + tx] = tile[tx][ty + i * 8];
}

// ---------------------------------------------------------------------------
// Kernel 2: 64b x 32o tile per block. lut/mapping accesses are wave-uniform
// (readfirstlane on the o-group) -> scalar loads, no LDS staging; level-0 of
// the binary fold reads lut straight from SGPRs. Results transposed through
// LDS so global stores are full 128B lines.
// ---------------------------------------------------------------------------
__global__ __launch_bounds__(256, 4) void lut_fwd_t(const float* __restrict__ xT,
                                                    const float* __restrict__ lut,
                                                    const int* __restrict__ mapping,
                                                    float* __restrict__ out) {
    __shared__ float tile[BT][OT + 1];       // +1 pad: conflict-free writes
    const int tid = threadIdx.x;
    const int tb  = tid & (BT - 1);
    // tid>>6 is wave-uniform (wave=64); force so lut/mapping go scalar path
    const int tg  = __builtin_amdgcn_readfirstlane(tid >> 6);
    const int b0  = blockIdx.x * BT;
    const int o0  = blockIdx.y * OT;
    const int b   = b0 + tb;

#pragma unroll
    for (int i = 0; i < OPT; i++) {
        const int o = o0 + tg * OPT + i;     // wave-uniform
        const float* __restrict__ lr = lut + (size_t)o * NENT;
        const int*   __restrict__ mp = mapping + (size_t)o * NBITS;

        // 6 coalesced gathers (mp[j] uniform -> SGPR base, +tb vector offset)
        float xv[NBITS];
#pragma unroll
        for (int j = 0; j < NBITS; j++)
            xv[j] = xT[(size_t)mp[j] * B_DIM + b];

        // level 0: contract bit 0 straight out of the (scalar-loaded) lut row
        float w[NENT / 2];
        {
            const float xj = xv[0], om = 1.0f - xj;
#pragma unroll
            for (int m = 0; m < NENT / 2; m++)
                w[m] = fmaf(lr[2 * m + 1], xj, lr[2 * m] * om);
        }
        // levels 1..5: in-register binary fold
#pragma unroll
        for (int j = 1; j < NBITS; j++) {
            const float xj = xv[j], om = 1.0f - xj;
#pragma unroll
            for (int m = 0; m < (NENT >> (j + 1)); m++)
                w[m] = fmaf(w[2 * m + 1], xj, w[2 * m] * om);
        }
        tile[tb][tg * OPT + i] = w[0];
    }
    __syncthreads();

    // cooperative store: each wave covers 2 full 128B lines per iteration
#pragma unroll
    for (int s = 0; s < (BT * OT) / 256; s++) {
        const int f  = s * 256 + tid;
        const int bb = f >> 5;               // f / OT
        const int cc = f & (OT - 1);
        out[(size_t)(b0 + bb) * OUT_DIM + o0 + cc] = tile[bb][cc];
    }
}

// ---------------------------------------------------------------------------
// Fallback (ws too small for xT): round-1 kernel, direct strided gather.
// ---------------------------------------------------------------------------
__global__ __launch_bounds__(256) void lut_fwd_fallback(const float* __restrict__ x,
                                                        const float* __restrict__ lut,
                                                        const int* __restrict__ mapping,
                                                        float* __restrict__ out) {
    __shared__ float slut[NENT];
    __shared__ int   smap[NBITS];
    const int o = blockIdx.y;
    const int b = blockIdx.x * 256 + threadIdx.x;
    if (threadIdx.x < NENT)  slut[threadIdx.x] = lut[o * NENT + threadIdx.x];
    if (threadIdx.x < NBITS) smap[threadIdx.x] = mapping[o * NBITS + threadIdx.x];
    __syncthreads();
    float xv[NBITS];
#pragma unroll
    for (int j = 0; j < NBITS; j++) xv[j] = x[(size_t)b * IN_DIM + smap[j]];
    float v[NENT];
#pragma unroll
    for (int k = 0; k < NENT; k++) v[k] = slut[k];
#pragma unroll
    for (int j = 0; j < NBITS; j++) {
        const float xj = xv[j], om = 1.0f - xj;
#pragma unroll
        for (int m = 0; m < (NENT >> (j + 1)); m++)
            v[m] = fmaf(v[2 * m + 1], xj, v[2 * m] * om);
    }
    out[(size_t)b * OUT_DIM + o] = v[0];
}

extern "C" void kernel_launch(void* const* d_in, const int* in_sizes, int n_in,
                              void* d_out, int out_size, void* d_ws, size_t ws_size,
                              hipStream_t stream) {
    const float* x       = (const float*)d_in[0];
    const float* lut     = (const float*)d_in[1];
    const int*   mapping = (const int*)d_in[2];
    float*       out     = (float*)d_out;

    const size_t xt_bytes = (size_t)B_DIM * IN_DIM * sizeof(float);

    if (ws_size >= xt_bytes) {
        float* xT = (float*)d_ws;
        const dim3 tgrid(IN_DIM / 32, B_DIM / 32);
        transpose_x<<<tgrid, 256, 0, stream>>>(x, xT);
        const dim3 grid(B_DIM / BT, OUT_DIM / OT);   // 16 x 64 = 1024 blocks
        lut_fwd_t<<<grid, 256, 0, stream>>>(xT, lut, mapping, out);
    } else {
        const dim3 grid(B_DIM / 256, OUT_DIM);
        lut_fwd_fallback<<<grid, 256, 0, stream>>>(x, lut, mapping, out);
    }
}

// Round 3
// 69.780 us; speedup vs baseline: 1.1053x; 1.1031x over previous
//
#include <hip/hip_runtime.h>

#define B_DIM   1024
#define IN_DIM  1024
#define OUT_DIM 2048
#define NBITS   6
#define NENT    64   // 1 << NBITS

#define OB   256     // o per block (== blockDim.x)
#define BB   16      // b per block
#define LROW 65      // padded lut row stride in words -> conflict-free row pull
// LDS words needed: max(OB*LROW, BB*IN_DIM) = max(16640, 16384) = 16640 (65 KiB)

// Single fused kernel. Layout: o in the lane dim (coalesced lut loads + out
// stores), b uniform per iteration (x rows staged coalesced into LDS, per-bit
// gathers are random-bank LDS reads ~ free). Each thread owns one o: its lut
// row is pulled to registers ONCE, converted to multilinear coefficients
//   c_S = finite-difference transform of lut row  (out = sum_S c_S * prod x_j)
// so per-(b,o) evaluation is a 63-FMA Horner binary fold.
__global__ __launch_bounds__(256, 2) void lut_fused(
    const float* __restrict__ x,
    const float* __restrict__ lut,
    const int*   __restrict__ mapping,
    float*       __restrict__ out)
{
    __shared__ __align__(16) float smem[OB * LROW];
    const int tid = threadIdx.x;
    const int o0  = blockIdx.x * OB;
    const int b0  = blockIdx.y * BB;
    const int o   = o0 + tid;

    // ---- stage lut tile (coalesced float4) into padded LDS ----
    const float4* lsrc = (const float4*)(lut + (size_t)o0 * NENT);
#pragma unroll
    for (int i = 0; i < (OB * NENT / 4) / 256; i++) {   // 16 iters
        const int f   = i * 256 + tid;                  // float4 index
        const float4 val = lsrc[f];
        const int ow  = f >> 4;                         // 16 float4 per row
        const int kw  = (f & 15) * 4;
        float* d = &smem[ow * LROW + kw];               // padded -> scalar stores
        d[0] = val.x; d[1] = val.y; d[2] = val.z; d[3] = val.w;
    }

    // mapping for my o (reused across all b of this block)
    int mp[NBITS];
#pragma unroll
    for (int j = 0; j < NBITS; j++) mp[j] = mapping[(size_t)o * NBITS + j];

    __syncthreads();

    // ---- pull my lut row (stride-65: bank (tid+k)%32, 2 lanes/bank = free) ----
    float v[NENT];
#pragma unroll
    for (int k = 0; k < NENT; k++) v[k] = smem[tid * LROW + k];

    // ---- in-register finite-difference transform: per bit j, hi -= lo ----
#pragma unroll
    for (int j = 0; j < NBITS; j++) {
#pragma unroll
        for (int k = 0; k < NENT; k++) {
            if ((k >> j) & 1) v[k] -= v[k ^ (1 << j)];
        }
    }

    __syncthreads();   // everyone done reading lut region before overwrite

    // ---- stage x tile (BB rows, coalesced float4 -> unpadded LDS) ----
    const float4* xsrc = (const float4*)(x + (size_t)b0 * IN_DIM);
    float4* xdst = (float4*)smem;
#pragma unroll
    for (int i = 0; i < (BB * IN_DIM / 4) / 256; i++) { // 16 iters
        const int f = i * 256 + tid;
        xdst[f] = xsrc[f];
    }
    __syncthreads();

    // ---- main loop: 6 LDS gathers + 63-FMA Horner per output ----
#pragma unroll 4
    for (int bi = 0; bi < BB; bi++) {
        const float* xr = &smem[bi * IN_DIM];           // bi uniform per iter
        float xv[NBITS];
#pragma unroll
        for (int j = 0; j < NBITS; j++) xv[j] = xr[mp[j]];

        float w[NENT / 2];
        {
            const float xj = xv[0];
#pragma unroll
            for (int m = 0; m < NENT / 2; m++)
                w[m] = fmaf(xj, v[2 * m + 1], v[2 * m]);
        }
#pragma unroll
        for (int j = 1; j < NBITS; j++) {
            const float xj = xv[j];
#pragma unroll
            for (int m = 0; m < (NENT >> (j + 1)); m++)
                w[m] = fmaf(xj, w[2 * m + 1], w[2 * m]);
        }
        out[(size_t)(b0 + bi) * OUT_DIM + o] = w[0];
    }
}

extern "C" void kernel_launch(void* const* d_in, const int* in_sizes, int n_in,
                              void* d_out, int out_size, void* d_ws, size_t ws_size,
                              hipStream_t stream) {
    const float* x       = (const float*)d_in[0];
    const float* lut     = (const float*)d_in[1];
    const int*   mapping = (const int*)d_in[2];
    float*       out     = (float*)d_out;
    (void)d_ws; (void)ws_size;

    const dim3 grid(OUT_DIM / OB, B_DIM / BB);   // 8 x 64 = 512 blocks, 2/CU
    lut_fused<<<grid, 256, 0, stream>>>(x, lut, mapping, out);
}